// Round 4
// baseline (252.518 us; speedup 1.0000x reference)
//
#include <hip/hip_runtime.h>
#include <hip/hip_bf16.h>

#define EPSF 1e-8f

typedef __attribute__((ext_vector_type(8))) short short8;
typedef __attribute__((ext_vector_type(4))) float floatx4;

__device__ inline unsigned short f2bf(float v) {
    union { float f; unsigned int u; } un; un.f = v;
    unsigned int r = (un.u + 0x7fffu + ((un.u >> 16) & 1u)) >> 16;
    return (unsigned short)r;
}
__device__ inline float bf2f(unsigned short u) {
    union { unsigned int i; float f; } un; un.i = ((unsigned int)u) << 16;
    return un.f;
}

// block = 256 threads (4 waves). Sum v over the block, broadcast to all threads.
__device__ inline float block_sum256(float v, float* lds4) {
    #pragma unroll
    for (int o = 32; o > 0; o >>= 1) v += __shfl_down(v, o, 64);
    int w = threadIdx.x >> 6, l = threadIdx.x & 63;
    if (l == 0) lds4[w] = v;
    __syncthreads();
    float tot = lds4[0] + lds4[1] + lds4[2] + lds4[3];
    __syncthreads();
    return tot;
}

// --- K_FRONT: fused prep (xnb=bf16(sgn*f), xh=|h|) + W->bf16 + row histogram.
// blocks [0,N): prep node b; [N,N+256): conv W row-block; [N+256,N+384): hist.
__global__ __launch_bounds__(256) void k_front(
        const float* __restrict__ x, const float* __restrict__ Ws,
        const float* __restrict__ Wn, const int* __restrict__ ei,
        unsigned short* __restrict__ xnb, float* __restrict__ xh,
        unsigned short* __restrict__ Wsb, unsigned short* __restrict__ Wnb,
        int* __restrict__ hist, int N, int E) {
    int b = blockIdx.x, t = threadIdx.x;
    if (b < N) {
        float h = x[(size_t)b * 257 + 256];
        float sgn = (h < 0.f) ? -1.f : 1.f;    // sign(0) -> 1 per reference
        float v = x[(size_t)b * 257 + t] * sgn;
        xnb[(size_t)b * 256 + t] = f2bf(v);
        if (t == 0) xh[b] = h * sgn;
    } else if (b < N + 256) {
        int idx = (b - N) * 256 + t;
        Wsb[idx] = f2bf(Ws[idx]);
        Wnb[idx] = f2bf(Wn[idx]);
    } else {
        for (int e = (b - N - 256) * 256 + t; e < E; e += 128 * 256)
            atomicAdd(&hist[ei[e]], 1);
    }
}

// --- K2 v2: fused double GEMM + row-normalize. 16 rows/block, 4 waves,
// wave w owns cols [64w,64w+64) of BOTH matrices. NO LDS staging / no barrier
// in the K-loop: A-frags direct from global (8KB tile, L1-served; all 4 waves
// share the same rows). W rows L2-resident (256KB total).
__global__ __launch_bounds__(256) void k_gemm2(
        const unsigned short* __restrict__ A,
        const unsigned short* __restrict__ Wsb,
        const unsigned short* __restrict__ Wnb,
        float* __restrict__ out, unsigned short* __restrict__ yb, int N) {
    __shared__ float pss[4][2][16];            // [wave][mat][row] partial ss
    int tid = threadIdx.x;
    int wave = tid >> 6, lane = tid & 63;
    int quad = lane >> 4, l16 = lane & 15;
    int row0 = blockIdx.x * 16;
    int arow = row0 + l16; if (arow >= N) arow = N - 1;

    const unsigned short* Ap  = A   + (size_t)arow * 256 + quad * 8;
    const unsigned short* WpS = Wsb + (size_t)(wave * 64 + l16) * 256 + quad * 8;
    const unsigned short* WpN = Wnb + (size_t)(wave * 64 + l16) * 256 + quad * 8;

    floatx4 acc[2][4];                         // [mat][group g: cols 16g..16g+15]
    #pragma unroll
    for (int m = 0; m < 2; ++m)
        #pragma unroll
        for (int g = 0; g < 4; ++g) acc[m][g] = floatx4{0.f,0.f,0.f,0.f};

    #pragma unroll 2
    for (int ks = 0; ks < 256; ks += 32) {
        short8 a = *reinterpret_cast<const short8*>(Ap + ks);
        #pragma unroll
        for (int g = 0; g < 4; ++g) {
            short8 ws = *reinterpret_cast<const short8*>(WpS + (size_t)g * 16 * 256 + ks);
            short8 wn = *reinterpret_cast<const short8*>(WpN + (size_t)g * 16 * 256 + ks);
            acc[0][g] = __builtin_amdgcn_mfma_f32_16x16x32_bf16(a, ws, acc[0][g], 0, 0, 0);
            acc[1][g] = __builtin_amdgcn_mfma_f32_16x16x32_bf16(a, wn, acc[1][g], 0, 0, 0);
        }
    }

    // row sum-of-squares: lane holds C[row=quad*4+reg][col=16g+l16] (+64*wave).
    // reduce squares over l16 (16 lanes within the quad), then over waves via LDS.
    #pragma unroll
    for (int m = 0; m < 2; ++m) {
        float s[4];
        #pragma unroll
        for (int reg = 0; reg < 4; ++reg) {
            float v = 0.f;
            #pragma unroll
            for (int g = 0; g < 4; ++g) v += acc[m][g][reg] * acc[m][g][reg];
            #pragma unroll
            for (int o = 8; o > 0; o >>= 1) v += __shfl_down(v, o, 64);
            s[reg] = v;                        // valid at l16 == 0
        }
        if (l16 == 0) {
            #pragma unroll
            for (int reg = 0; reg < 4; ++reg)
                pss[wave][m][quad * 4 + reg] = s[reg];
        }
    }
    __syncthreads();

    // scale + store (C/D: col = l16 + 16g + 64*wave, row = quad*4 + reg)
    #pragma unroll
    for (int m = 0; m < 2; ++m)
        #pragma unroll
        for (int reg = 0; reg < 4; ++reg) {
            int r16 = quad * 4 + reg;
            int gr = row0 + r16;
            if (gr >= N) continue;
            float ss = pss[0][m][r16] + pss[1][m][r16]
                     + pss[2][m][r16] + pss[3][m][r16];
            bool zero = (ss == 0.f);
            float scale = zero ? 0.f : (1.f / fmaxf(sqrtf(ss), EPSF));
            #pragma unroll
            for (int g = 0; g < 4; ++g) {
                int col = wave * 64 + 16 * g + l16;
                float val = zero ? 0.0625f : acc[m][g][reg] * scale;
                if (m == 0) out[(size_t)gr * 257 + col] = val;
                else        yb[(size_t)gr * 256 + col] = f2bf(val);
            }
        }
}

// --- S2: exclusive prefix sum (single block, wave-shfl scan, 1 barrier) ---
__global__ __launch_bounds__(1024) void k_scan(const int* __restrict__ hist,
        int* __restrict__ offs, int* __restrict__ cursor, int N) {
    __shared__ int wtot[16];
    int t = threadIdx.x, lane = t & 63, wv = t >> 6;
    int C = (N + 1023) >> 10;                  // per-thread chunk (<=32)
    int base = t * C;
    int vals[32];
    int s = 0;
    #pragma unroll
    for (int i = 0; i < 32; ++i) {
        if (i < C) {
            int idx = base + i;
            vals[i] = (idx < N) ? hist[idx] : 0;
            s += vals[i];
        }
    }
    int incl = s;
    #pragma unroll
    for (int o = 1; o < 64; o <<= 1) {
        int v = __shfl_up(incl, o, 64);
        if (lane >= o) incl += v;
    }
    if (lane == 63) wtot[wv] = incl;
    __syncthreads();
    int wbase = 0;
    for (int w = 0; w < wv; ++w) wbase += wtot[w];
    int run = wbase + incl - s;                // exclusive base for this thread
    #pragma unroll
    for (int i = 0; i < 32; ++i) {
        if (i < C) {
            int idx = base + i;
            if (idx < N) { offs[idx] = run; cursor[idx] = run; run += vals[i]; }
        }
    }
}

// --- S3: bucket edges by destination row: scol = cols sorted by row ---
__global__ __launch_bounds__(256) void k_bucket(const int* __restrict__ ei,
        int* __restrict__ cursor, int* __restrict__ scol, int E) {
    int e = blockIdx.x * 256 + threadIdx.x;
    if (e >= E) return;
    int r = ei[e], c = ei[E + e];
    int pos = atomicAdd(&cursor[r], 1);
    scol[pos] = c;
}

// --- S4: per-node gather-aggregate (no atomics) + fused combine epilogue ---
__global__ __launch_bounds__(256) void k_agg_combine(
        const int* __restrict__ offs, const int* __restrict__ hist,
        const int* __restrict__ scol, const unsigned short* __restrict__ yb,
        const float* __restrict__ xh, float* __restrict__ out, int N) {
    __shared__ float red[4][256];
    __shared__ float hred[4];
    __shared__ float lds4[4];
    int i = blockIdx.x, t = threadIdx.x;
    int wave = t >> 6, lane = t & 63;
    int beg = offs[i], deg = hist[i];
    float a0 = 0.f, a1 = 0.f, a2 = 0.f, a3 = 0.f, ah = 0.f;
    for (int e = beg + wave; e < beg + deg; e += 4) {
        int c = scol[e];
        ushort4 v = reinterpret_cast<const ushort4*>(yb + (size_t)c * 256)[lane];
        a0 += bf2f(v.x); a1 += bf2f(v.y); a2 += bf2f(v.z); a3 += bf2f(v.w);
        if (lane == 0) ah += xh[c];
    }
    red[wave][lane * 4 + 0] = a0;
    red[wave][lane * 4 + 1] = a1;
    red[wave][lane * 4 + 2] = a2;
    red[wave][lane * 4 + 3] = a3;
    if (lane == 0) hred[wave] = ah;
    __syncthreads();
    float num  = red[0][t] + red[1][t] + red[2][t] + red[3][t];
    float aggh = hred[0] + hred[1] + hred[2] + hred[3];
    __syncthreads();
    float cn = (deg > 0) ? (float)deg : 1.f;
    float mean = num / cn;
    float ss = block_sum256(mean * mean, lds4);
    float f = (ss == 0.f) ? 1.f : mean;        // no-in-edge node: zero_mask -> ones
    float nrm = (ss == 0.f) ? 16.f : sqrtf(ss);
    float of = f / fmaxf(nrm, EPSF);
    float oh = 1.f + aggh;
    float s = out[(size_t)i * 257 + t];        // self_trans f (from k_gemm2)
    float av = 0.5f * (s + of);                // t = 0.5/(0.5+1e-8) == 1.0f in fp32
    float ss2 = block_sum256(av * av, lds4);
    float f2 = (ss2 == 0.f) ? 1.f : av;
    float n2 = (ss2 == 0.f) ? 16.f : sqrtf(ss2);
    out[(size_t)i * 257 + t] = f2 / fmaxf(n2, EPSF);
    if (t == 0) out[(size_t)i * 257 + 256] = 0.5f * (xh[i] + oh);
}

extern "C" void kernel_launch(void* const* d_in, const int* in_sizes, int n_in,
                              void* d_out, int out_size, void* d_ws, size_t ws_size,
                              hipStream_t stream) {
    const float* x  = (const float*)d_in[0];
    const float* Ws = (const float*)d_in[1];
    const float* Wn = (const float*)d_in[2];
    const int*   ei = (const int*)d_in[3];
    int N = in_sizes[0] / 257;
    int E = in_sizes[3] / 2;
    float* out = (float*)d_out;

    char* ws = (char*)d_ws;
    size_t off = 0;
    auto alloc = [&](size_t bytes) {
        void* p = ws + off;
        off = (off + bytes + 255) & ~(size_t)255;
        return p;
    };
    unsigned short* xnb = (unsigned short*)alloc((size_t)N * 256 * 2);
    unsigned short* Wsb = (unsigned short*)alloc(256 * 256 * 2);
    unsigned short* Wnb = (unsigned short*)alloc(256 * 256 * 2);
    float* xh   = (float*)alloc((size_t)N * 4);
    unsigned short* yb = (unsigned short*)alloc((size_t)N * 256 * 2);
    int* hist   = (int*)alloc((size_t)N * 4);
    int* offs   = (int*)alloc((size_t)N * 4);
    int* cursor = (int*)alloc((size_t)N * 4);
    int* scol   = (int*)alloc((size_t)E * 4);

    hipMemsetAsync(hist, 0, (size_t)N * 4, stream);

    // fused prep + W-convert + histogram
    hipLaunchKernelGGL(k_front, dim3(N + 256 + 128), dim3(256), 0, stream,
                       x, Ws, Wn, ei, xnb, xh, Wsb, Wnb, hist, N, E);
    // CSR finish
    hipLaunchKernelGGL(k_scan, dim3(1), dim3(1024), 0, stream, hist, offs, cursor, N);
    hipLaunchKernelGGL(k_bucket, dim3((E + 255) / 256), dim3(256), 0, stream, ei, cursor, scol, E);
    // fused double GEMM + row-normalize
    hipLaunchKernelGGL(k_gemm2, dim3((N + 15) / 16), dim3(256), 0, stream,
                       xnb, Wsb, Wnb, out, yb, N);
    // gather-aggregate + combine
    hipLaunchKernelGGL(k_agg_combine, dim3(N), dim3(256), 0, stream,
                       offs, hist, scol, yb, xh, out, N);
}

// Round 5
// 228.831 us; speedup vs baseline: 1.1035x; 1.1035x over previous
//
#include <hip/hip_runtime.h>
#include <hip/hip_bf16.h>

#define EPSF 1e-8f

typedef __attribute__((ext_vector_type(8))) short short8;
typedef __attribute__((ext_vector_type(4))) float floatx4;

__device__ inline unsigned short f2bf(float v) {
    union { float f; unsigned int u; } un; un.f = v;
    unsigned int r = (un.u + 0x7fffu + ((un.u >> 16) & 1u)) >> 16;
    return (unsigned short)r;
}
__device__ inline float bf2f(unsigned short u) {
    union { unsigned int i; float f; } un; un.i = ((unsigned int)u) << 16;
    return un.f;
}

// --- K_FRONT: fused prep (xnb=bf16(sgn*f), xh=|h|) + W->bf16 + row histogram.
// blocks [0,N): prep node b; [N,N+256): conv W row-block; [N+256,N+384): hist.
__global__ __launch_bounds__(256) void k_front(
        const float* __restrict__ x, const float* __restrict__ Ws,
        const float* __restrict__ Wn, const int* __restrict__ ei,
        unsigned short* __restrict__ xnb, float* __restrict__ xh,
        unsigned short* __restrict__ Wsb, unsigned short* __restrict__ Wnb,
        int* __restrict__ hist, int N, int E) {
    int b = blockIdx.x, t = threadIdx.x;
    if (b < N) {
        float h = x[(size_t)b * 257 + 256];
        float sgn = (h < 0.f) ? -1.f : 1.f;    // sign(0) -> 1 per reference
        float v = x[(size_t)b * 257 + t] * sgn;
        xnb[(size_t)b * 256 + t] = f2bf(v);
        if (t == 0) xh[b] = h * sgn;
    } else if (b < N + 256) {
        int idx = (b - N) * 256 + t;
        Wsb[idx] = f2bf(Ws[idx]);
        Wnb[idx] = f2bf(Wn[idx]);
    } else {
        for (int e = (b - N - 256) * 256 + t; e < E; e += 128 * 256)
            atomicAdd(&hist[ei[e]], 1);
    }
}

// --- K2 v3: fused double GEMM + row-normalize. 16 rows/block, 512 threads
// (8 waves): waves 0-3 compute W_self cols [64w,64w+64) -> selfb (fp32),
// waves 4-7 compute W_neigh -> yb (bf16). 10000 waves total (vs 2500 in v2)
// so occupancy is VGPR-capped, not grid-capped; half the loads per wave.
__global__ __launch_bounds__(512) void k_gemm2(
        const unsigned short* __restrict__ A,
        const unsigned short* __restrict__ Wsb,
        const unsigned short* __restrict__ Wnb,
        float* __restrict__ selfb, unsigned short* __restrict__ yb, int N) {
    __shared__ float pss[8][16];               // [wave][row] partial ss
    int tid = threadIdx.x;
    int wave = tid >> 6, lane = tid & 63;
    int quad = lane >> 4, l16 = lane & 15;
    int mat = wave >> 2, wq = wave & 3;
    int row0 = blockIdx.x * 16;
    int arow = row0 + l16; if (arow >= N) arow = N - 1;

    const unsigned short* Ap = A + (size_t)arow * 256 + quad * 8;
    const unsigned short* W  = mat ? Wnb : Wsb;
    const unsigned short* Wp = W + (size_t)(wq * 64 + l16) * 256 + quad * 8;

    floatx4 acc[4];                            // group g: cols 16g..16g+15
    #pragma unroll
    for (int g = 0; g < 4; ++g) acc[g] = floatx4{0.f,0.f,0.f,0.f};

    #pragma unroll 2
    for (int ks = 0; ks < 256; ks += 32) {
        short8 a = *reinterpret_cast<const short8*>(Ap + ks);
        #pragma unroll
        for (int g = 0; g < 4; ++g) {
            short8 w = *reinterpret_cast<const short8*>(Wp + (size_t)g * 16 * 256 + ks);
            acc[g] = __builtin_amdgcn_mfma_f32_16x16x32_bf16(a, w, acc[g], 0, 0, 0);
        }
    }

    // per-wave row sum-of-squares partials (C/D: col=16g+l16, row=quad*4+reg)
    float s[4];
    #pragma unroll
    for (int reg = 0; reg < 4; ++reg) {
        float v = 0.f;
        #pragma unroll
        for (int g = 0; g < 4; ++g) v += acc[g][reg] * acc[g][reg];
        #pragma unroll
        for (int o = 8; o > 0; o >>= 1) v += __shfl_down(v, o, 64);
        s[reg] = v;                            // valid at l16 == 0
    }
    if (l16 == 0) {
        #pragma unroll
        for (int reg = 0; reg < 4; ++reg) pss[wave][quad * 4 + reg] = s[reg];
    }
    __syncthreads();

    #pragma unroll
    for (int reg = 0; reg < 4; ++reg) {
        int r16 = quad * 4 + reg;
        int gr = row0 + r16;
        if (gr >= N) continue;
        int wb = mat * 4;
        float ss = pss[wb][r16] + pss[wb + 1][r16] + pss[wb + 2][r16] + pss[wb + 3][r16];
        bool zero = (ss == 0.f);
        float scale = zero ? 0.f : (1.f / fmaxf(sqrtf(ss), EPSF));
        #pragma unroll
        for (int g = 0; g < 4; ++g) {
            int col = wq * 64 + 16 * g + l16;
            float val = zero ? 0.0625f : acc[g][reg] * scale;
            if (mat == 0) selfb[(size_t)gr * 256 + col] = val;
            else          yb[(size_t)gr * 256 + col] = f2bf(val);
        }
    }
}

// --- S2: exclusive prefix sum (single block, wave-shfl scan, 1 barrier) ---
__global__ __launch_bounds__(1024) void k_scan(const int* __restrict__ hist,
        int* __restrict__ offs, int* __restrict__ cursor, int N) {
    __shared__ int wtot[16];
    int t = threadIdx.x, lane = t & 63, wv = t >> 6;
    int C = (N + 1023) >> 10;                  // per-thread chunk (<=32)
    int base = t * C;
    int vals[32];
    int s = 0;
    #pragma unroll
    for (int i = 0; i < 32; ++i) {
        if (i < C) {
            int idx = base + i;
            vals[i] = (idx < N) ? hist[idx] : 0;
            s += vals[i];
        }
    }
    int incl = s;
    #pragma unroll
    for (int o = 1; o < 64; o <<= 1) {
        int v = __shfl_up(incl, o, 64);
        if (lane >= o) incl += v;
    }
    if (lane == 63) wtot[wv] = incl;
    __syncthreads();
    int wbase = 0;
    for (int w = 0; w < wv; ++w) wbase += wtot[w];
    int run = wbase + incl - s;                // exclusive base for this thread
    #pragma unroll
    for (int i = 0; i < 32; ++i) {
        if (i < C) {
            int idx = base + i;
            if (idx < N) { offs[idx] = run; cursor[idx] = run; run += vals[i]; }
        }
    }
}

// --- S3: bucket edges by destination row: scol = cols sorted by row ---
__global__ __launch_bounds__(256) void k_bucket(const int* __restrict__ ei,
        int* __restrict__ cursor, int* __restrict__ scol, int E) {
    int e = blockIdx.x * 256 + threadIdx.x;
    if (e >= E) return;
    int r = ei[e], c = ei[E + e];
    int pos = atomicAdd(&cursor[r], 1);
    scol[pos] = c;
}

// --- S4 v2: ONE WAVE PER NODE. Lane owns cols [4*lane,4*lane+4). Gather +
// mean + normalize + self-average + final normalize, all wave-local via
// shfl_xor butterflies. No LDS, no barriers. Writes the whole out row.
__global__ __launch_bounds__(256) void k_agg_combine(
        const int* __restrict__ offs, const int* __restrict__ hist,
        const int* __restrict__ scol, const unsigned short* __restrict__ yb,
        const float* __restrict__ xh, const float* __restrict__ selfb,
        float* __restrict__ out, int N) {
    int wid = (blockIdx.x * 256 + threadIdx.x) >> 6;   // global wave = node id
    if (wid >= N) return;
    int lane = threadIdx.x & 63;
    int beg = offs[wid], deg = hist[wid];
    float a0 = 0.f, a1 = 0.f, a2 = 0.f, a3 = 0.f;
    float b0 = 0.f, b1 = 0.f, b2 = 0.f, b3 = 0.f, ah = 0.f;
    int e = beg, end = beg + deg;
    for (; e + 1 < end; e += 2) {              // unroll x2: two gathers in flight
        int c0 = scol[e], c1 = scol[e + 1];
        ushort4 v0 = *reinterpret_cast<const ushort4*>(yb + (size_t)c0 * 256 + lane * 4);
        ushort4 v1 = *reinterpret_cast<const ushort4*>(yb + (size_t)c1 * 256 + lane * 4);
        a0 += bf2f(v0.x); a1 += bf2f(v0.y); a2 += bf2f(v0.z); a3 += bf2f(v0.w);
        b0 += bf2f(v1.x); b1 += bf2f(v1.y); b2 += bf2f(v1.z); b3 += bf2f(v1.w);
        if (lane == 0) ah += xh[c0] + xh[c1];
    }
    if (e < end) {
        int c0 = scol[e];
        ushort4 v0 = *reinterpret_cast<const ushort4*>(yb + (size_t)c0 * 256 + lane * 4);
        a0 += bf2f(v0.x); a1 += bf2f(v0.y); a2 += bf2f(v0.z); a3 += bf2f(v0.w);
        if (lane == 0) ah += xh[c0];
    }
    a0 += b0; a1 += b1; a2 += b2; a3 += b3;

    float cn = (deg > 0) ? (float)deg : 1.f;
    float m0 = a0 / cn, m1 = a1 / cn, m2 = a2 / cn, m3 = a3 / cn;
    float ss = m0 * m0 + m1 * m1 + m2 * m2 + m3 * m3;
    #pragma unroll
    for (int o = 32; o > 0; o >>= 1) ss += __shfl_xor(ss, o, 64);
    bool z = (ss == 0.f);                      // no-in-edge node: zero_mask -> ones
    float inv = 1.f / fmaxf(z ? 16.f : sqrtf(ss), EPSF);
    float o0 = (z ? 1.f : m0) * inv, o1 = (z ? 1.f : m1) * inv;
    float o2 = (z ? 1.f : m2) * inv, o3 = (z ? 1.f : m3) * inv;

    float4 s4 = reinterpret_cast<const float4*>(selfb + (size_t)wid * 256)[lane];
    float v0 = 0.5f * (s4.x + o0), v1 = 0.5f * (s4.y + o1);   // t==1.0f in fp32
    float v2 = 0.5f * (s4.z + o2), v3 = 0.5f * (s4.w + o3);
    float ss2 = v0 * v0 + v1 * v1 + v2 * v2 + v3 * v3;
    #pragma unroll
    for (int o = 32; o > 0; o >>= 1) ss2 += __shfl_xor(ss2, o, 64);
    bool z2 = (ss2 == 0.f);
    float inv2 = 1.f / fmaxf(z2 ? 16.f : sqrtf(ss2), EPSF);

    float* op = out + (size_t)wid * 257 + lane * 4;
    op[0] = (z2 ? 1.f : v0) * inv2;
    op[1] = (z2 ? 1.f : v1) * inv2;
    op[2] = (z2 ? 1.f : v2) * inv2;
    op[3] = (z2 ? 1.f : v3) * inv2;
    if (lane == 0) out[(size_t)wid * 257 + 256] = 0.5f * (xh[wid] + 1.f + ah);
}

extern "C" void kernel_launch(void* const* d_in, const int* in_sizes, int n_in,
                              void* d_out, int out_size, void* d_ws, size_t ws_size,
                              hipStream_t stream) {
    const float* x  = (const float*)d_in[0];
    const float* Ws = (const float*)d_in[1];
    const float* Wn = (const float*)d_in[2];
    const int*   ei = (const int*)d_in[3];
    int N = in_sizes[0] / 257;
    int E = in_sizes[3] / 2;
    float* out = (float*)d_out;

    char* ws = (char*)d_ws;
    size_t off = 0;
    auto alloc = [&](size_t bytes) {
        void* p = ws + off;
        off = (off + bytes + 255) & ~(size_t)255;
        return p;
    };
    unsigned short* xnb = (unsigned short*)alloc((size_t)N * 256 * 2);
    unsigned short* Wsb = (unsigned short*)alloc(256 * 256 * 2);
    unsigned short* Wnb = (unsigned short*)alloc(256 * 256 * 2);
    float* xh    = (float*)alloc((size_t)N * 4);
    unsigned short* yb = (unsigned short*)alloc((size_t)N * 256 * 2);
    float* selfb = (float*)alloc((size_t)N * 256 * 4);
    int* hist   = (int*)alloc((size_t)N * 4);
    int* offs   = (int*)alloc((size_t)N * 4);
    int* cursor = (int*)alloc((size_t)N * 4);
    int* scol   = (int*)alloc((size_t)E * 4);

    hipMemsetAsync(hist, 0, (size_t)N * 4, stream);

    // fused prep + W-convert + histogram
    hipLaunchKernelGGL(k_front, dim3(N + 256 + 128), dim3(256), 0, stream,
                       x, Ws, Wn, ei, xnb, xh, Wsb, Wnb, hist, N, E);
    // CSR finish
    hipLaunchKernelGGL(k_scan, dim3(1), dim3(1024), 0, stream, hist, offs, cursor, N);
    hipLaunchKernelGGL(k_bucket, dim3((E + 255) / 256), dim3(256), 0, stream, ei, cursor, scol, E);
    // fused double GEMM + row-normalize (8 waves/block: 4 self, 4 neigh)
    hipLaunchKernelGGL(k_gemm2, dim3((N + 15) / 16), dim3(512), 0, stream,
                       xnb, Wsb, Wnb, selfb, yb, N);
    // wave-per-node gather-aggregate + combine (no LDS, no barriers)
    hipLaunchKernelGGL(k_agg_combine, dim3((N + 3) / 4), dim3(256), 0, stream,
                       offs, hist, scol, yb, xh, selfb, out, N);
}

// Round 6
// 205.246 us; speedup vs baseline: 1.2303x; 1.1149x over previous
//
#include <hip/hip_runtime.h>
#include <hip/hip_bf16.h>

#define EPSF 1e-8f

typedef __attribute__((ext_vector_type(8))) short short8;
typedef __attribute__((ext_vector_type(4))) float floatx4;
typedef __attribute__((ext_vector_type(2))) float floatx2;

__device__ inline unsigned short f2bf(float v) {
    union { float f; unsigned int u; } un; un.f = v;
    unsigned int r = (un.u + 0x7fffu + ((un.u >> 16) & 1u)) >> 16;
    return (unsigned short)r;
}

// ---- fp8 e4m3 (OCP) encode/decode: HW cvt on gfx950, SW fallback otherwise ----
__device__ inline unsigned char f2fp8(float v) {
#if __has_builtin(__builtin_amdgcn_cvt_pk_fp8_f32)
    return (unsigned char)(__builtin_amdgcn_cvt_pk_fp8_f32(v, 0.f, 0u, false) & 0xff);
#else
    union { float f; unsigned u; } x; x.f = v;
    unsigned s = x.u >> 31; x.u &= 0x7fffffffu;
    if (x.f != x.f || x.f == 0.f) return (unsigned char)(s << 7);
    int e = (int)((x.u >> 23) & 0xff) - 127 + 7;
    unsigned m = x.u & 0x7fffffu;
    unsigned char r;
    if (e >= 1) {
        unsigned keep = m >> 20, rest = m & 0xfffffu;
        keep += (rest > 0x80000u) || (rest == 0x80000u && (keep & 1));
        if (keep == 8) { keep = 0; e += 1; }
        if (e > 15) { e = 15; keep = 6; }          // clamp to 448
        r = (unsigned char)((e << 3) | keep);
    } else {
        int q = (int)(x.f * 512.f + 0.5f);         // subnormal: val * 2^9
        if (q > 7) r = 0x08; else r = (unsigned char)q;
    }
    return (unsigned char)(r | (s << 7));
#endif
}
__device__ inline floatx2 fp8x2_to_f32(unsigned int u, bool word) {
#if __has_builtin(__builtin_amdgcn_cvt_pk_f32_fp8)
    return word ? __builtin_amdgcn_cvt_pk_f32_fp8(u, true)
                : __builtin_amdgcn_cvt_pk_f32_fp8(u, false);
#else
    floatx2 out;
    #pragma unroll
    for (int i = 0; i < 2; ++i) {
        unsigned char b = (u >> ((word ? 16 : 0) + 8 * i)) & 0xff;
        unsigned s = (b >> 7) & 1, e = (b >> 3) & 15, m = b & 7;
        float v;
        if (e) { union { unsigned u2; float f; } x; x.u2 = (s << 31) | ((e + 120u) << 23) | (m << 20); v = x.f; }
        else   { v = (s ? -1.f : 1.f) * (float)m * 0.001953125f; }
        out[i] = v;
    }
    return out;
#endif
}

// --- K_FRONT: fused prep (xnb=bf16(sgn*f), xh=|h|) + W->bf16 + row histogram.
__global__ __launch_bounds__(256) void k_front(
        const float* __restrict__ x, const float* __restrict__ Ws,
        const float* __restrict__ Wn, const int* __restrict__ ei,
        unsigned short* __restrict__ xnb, float* __restrict__ xh,
        unsigned short* __restrict__ Wsb, unsigned short* __restrict__ Wnb,
        int* __restrict__ hist, int N, int E) {
    int b = blockIdx.x, t = threadIdx.x;
    if (b < N) {
        float h = x[(size_t)b * 257 + 256];
        float sgn = (h < 0.f) ? -1.f : 1.f;    // sign(0) -> 1 per reference
        float v = x[(size_t)b * 257 + t] * sgn;
        xnb[(size_t)b * 256 + t] = f2bf(v);
        if (t == 0) xh[b] = h * sgn;
    } else if (b < N + 256) {
        int idx = (b - N) * 256 + t;
        Wsb[idx] = f2bf(Ws[idx]);
        Wnb[idx] = f2bf(Wn[idx]);
    } else {
        for (int e = (b - N - 256) * 256 + t; e < E; e += 128 * 256)
            atomicAdd(&hist[ei[e]], 1);
    }
}

// --- K2 v4: fused double GEMM + row-normalize. 32 rows/block, 512 threads
// (8 waves): waves 0-3 -> W_self -> selfb (fp32), waves 4-7 -> W_neigh -> yb8
// (fp8). A-tile staged ONCE in LDS (padded rows: ds_read_b128 ~4-way = cheap);
// each wave: 2 row-tiles x 4 col-groups = 8 MFMA per 4 W-loads + 2 ds_reads.
__global__ __launch_bounds__(512) void k_gemm2(
        const unsigned short* __restrict__ A,
        const unsigned short* __restrict__ Wsb,
        const unsigned short* __restrict__ Wnb,
        float* __restrict__ selfb, unsigned char* __restrict__ yb8, int N) {
    __shared__ unsigned short As[32][260];      // +4 shorts pad
    __shared__ float pss[8][32];                // [wave][row-in-tile] partial ss
    int tid = threadIdx.x;
    int wave = tid >> 6, lane = tid & 63;
    int quad = lane >> 4, l16 = lane & 15;
    int mat = wave >> 2, wq = wave & 3;
    int row0 = blockIdx.x * 32;

    // stage A-tile: 1024 chunks of 16B, 512 threads x 2
    #pragma unroll
    for (int i = 0; i < 2; ++i) {
        int c = i * 512 + tid;
        int r = c >> 5, col = (c & 31) * 8;
        int gr = row0 + r; if (gr >= N) gr = N - 1;
        *reinterpret_cast<short8*>(&As[r][col]) =
            *reinterpret_cast<const short8*>(A + (size_t)gr * 256 + col);
    }
    __syncthreads();

    const unsigned short* W  = mat ? Wnb : Wsb;
    const unsigned short* Wp = W + (size_t)(wq * 64 + l16) * 256 + quad * 8;

    floatx4 acc[2][4];                          // [row-tile][col-group]
    #pragma unroll
    for (int rt = 0; rt < 2; ++rt)
        #pragma unroll
        for (int g = 0; g < 4; ++g) acc[rt][g] = floatx4{0.f, 0.f, 0.f, 0.f};

    #pragma unroll 2
    for (int ks = 0; ks < 256; ks += 32) {
        short8 a0 = *reinterpret_cast<const short8*>(&As[l16][quad * 8 + ks]);
        short8 a1 = *reinterpret_cast<const short8*>(&As[16 + l16][quad * 8 + ks]);
        short8 w0 = *reinterpret_cast<const short8*>(Wp + (size_t)0 * 4096 + ks);
        short8 w1 = *reinterpret_cast<const short8*>(Wp + (size_t)1 * 4096 + ks);
        short8 w2 = *reinterpret_cast<const short8*>(Wp + (size_t)2 * 4096 + ks);
        short8 w3 = *reinterpret_cast<const short8*>(Wp + (size_t)3 * 4096 + ks);
        acc[0][0] = __builtin_amdgcn_mfma_f32_16x16x32_bf16(a0, w0, acc[0][0], 0, 0, 0);
        acc[1][0] = __builtin_amdgcn_mfma_f32_16x16x32_bf16(a1, w0, acc[1][0], 0, 0, 0);
        acc[0][1] = __builtin_amdgcn_mfma_f32_16x16x32_bf16(a0, w1, acc[0][1], 0, 0, 0);
        acc[1][1] = __builtin_amdgcn_mfma_f32_16x16x32_bf16(a1, w1, acc[1][1], 0, 0, 0);
        acc[0][2] = __builtin_amdgcn_mfma_f32_16x16x32_bf16(a0, w2, acc[0][2], 0, 0, 0);
        acc[1][2] = __builtin_amdgcn_mfma_f32_16x16x32_bf16(a1, w2, acc[1][2], 0, 0, 0);
        acc[0][3] = __builtin_amdgcn_mfma_f32_16x16x32_bf16(a0, w3, acc[0][3], 0, 0, 0);
        acc[1][3] = __builtin_amdgcn_mfma_f32_16x16x32_bf16(a1, w3, acc[1][3], 0, 0, 0);
    }

    // per-wave row ss partials (C/D: col=16g+l16 (+64wq), row=quad*4+reg)
    #pragma unroll
    for (int rt = 0; rt < 2; ++rt) {
        float s[4];
        #pragma unroll
        for (int reg = 0; reg < 4; ++reg) {
            float v = 0.f;
            #pragma unroll
            for (int g = 0; g < 4; ++g) v += acc[rt][g][reg] * acc[rt][g][reg];
            #pragma unroll
            for (int o = 8; o > 0; o >>= 1) v += __shfl_down(v, o, 64);
            s[reg] = v;                         // valid at l16 == 0
        }
        if (l16 == 0) {
            #pragma unroll
            for (int reg = 0; reg < 4; ++reg)
                pss[wave][rt * 16 + quad * 4 + reg] = s[reg];
        }
    }
    __syncthreads();

    int wb = mat * 4;
    #pragma unroll
    for (int rt = 0; rt < 2; ++rt)
        #pragma unroll
        for (int reg = 0; reg < 4; ++reg) {
            int r32 = rt * 16 + quad * 4 + reg;
            int gr = row0 + r32;
            if (gr >= N) continue;
            float ss = pss[wb][r32] + pss[wb + 1][r32]
                     + pss[wb + 2][r32] + pss[wb + 3][r32];
            bool zero = (ss == 0.f);
            float scale = zero ? 0.f : (1.f / fmaxf(sqrtf(ss), EPSF));
            #pragma unroll
            for (int g = 0; g < 4; ++g) {
                int col = wq * 64 + 16 * g + l16;
                float val = zero ? 0.0625f : acc[rt][g][reg] * scale;
                if (mat == 0) selfb[(size_t)gr * 256 + col] = val;
                else          yb8[(size_t)gr * 256 + col] = f2fp8(val);
            }
        }
}

// --- S2: exclusive prefix sum (single block, wave-shfl scan, 1 barrier) ---
__global__ __launch_bounds__(1024) void k_scan(const int* __restrict__ hist,
        int* __restrict__ offs, int* __restrict__ cursor, int N) {
    __shared__ int wtot[16];
    int t = threadIdx.x, lane = t & 63, wv = t >> 6;
    int C = (N + 1023) >> 10;
    int base = t * C;
    int vals[32];
    int s = 0;
    #pragma unroll
    for (int i = 0; i < 32; ++i) {
        if (i < C) {
            int idx = base + i;
            vals[i] = (idx < N) ? hist[idx] : 0;
            s += vals[i];
        }
    }
    int incl = s;
    #pragma unroll
    for (int o = 1; o < 64; o <<= 1) {
        int v = __shfl_up(incl, o, 64);
        if (lane >= o) incl += v;
    }
    if (lane == 63) wtot[wv] = incl;
    __syncthreads();
    int wbase = 0;
    for (int w = 0; w < wv; ++w) wbase += wtot[w];
    int run = wbase + incl - s;
    #pragma unroll
    for (int i = 0; i < 32; ++i) {
        if (i < C) {
            int idx = base + i;
            if (idx < N) { offs[idx] = run; cursor[idx] = run; run += vals[i]; }
        }
    }
}

// --- S3: bucket edges by destination row ---
__global__ __launch_bounds__(256) void k_bucket(const int* __restrict__ ei,
        int* __restrict__ cursor, int* __restrict__ scol, int E) {
    int e = blockIdx.x * 256 + threadIdx.x;
    if (e >= E) return;
    int r = ei[e], c = ei[E + e];
    int pos = atomicAdd(&cursor[r], 1);
    scol[pos] = c;
}

// --- S4: ONE WAVE PER NODE, fp8 gather (256B/edge). Wave-local epilogue. ---
__global__ __launch_bounds__(256) void k_agg_combine(
        const int* __restrict__ offs, const int* __restrict__ hist,
        const int* __restrict__ scol, const unsigned char* __restrict__ yb8,
        const float* __restrict__ xh, const float* __restrict__ selfb,
        float* __restrict__ out, int N) {
    int wid = (blockIdx.x * 256 + threadIdx.x) >> 6;   // global wave = node id
    if (wid >= N) return;
    int lane = threadIdx.x & 63;
    int beg = offs[wid], deg = hist[wid];
    float a0 = 0.f, a1 = 0.f, a2 = 0.f, a3 = 0.f;
    float b0 = 0.f, b1 = 0.f, b2 = 0.f, b3 = 0.f, ah = 0.f;
    int e = beg, end = beg + deg;
    for (; e + 1 < end; e += 2) {
        int c0 = scol[e], c1 = scol[e + 1];
        unsigned int u0 = *reinterpret_cast<const unsigned int*>(yb8 + (size_t)c0 * 256 + lane * 4);
        unsigned int u1 = *reinterpret_cast<const unsigned int*>(yb8 + (size_t)c1 * 256 + lane * 4);
        floatx2 l0 = fp8x2_to_f32(u0, false), h0 = fp8x2_to_f32(u0, true);
        floatx2 l1 = fp8x2_to_f32(u1, false), h1 = fp8x2_to_f32(u1, true);
        a0 += l0[0]; a1 += l0[1]; a2 += h0[0]; a3 += h0[1];
        b0 += l1[0]; b1 += l1[1]; b2 += h1[0]; b3 += h1[1];
        if (lane == 0) ah += xh[c0] + xh[c1];
    }
    if (e < end) {
        int c0 = scol[e];
        unsigned int u0 = *reinterpret_cast<const unsigned int*>(yb8 + (size_t)c0 * 256 + lane * 4);
        floatx2 l0 = fp8x2_to_f32(u0, false), h0 = fp8x2_to_f32(u0, true);
        a0 += l0[0]; a1 += l0[1]; a2 += h0[0]; a3 += h0[1];
        if (lane == 0) ah += xh[c0];
    }
    a0 += b0; a1 += b1; a2 += b2; a3 += b3;

    float cn = (deg > 0) ? (float)deg : 1.f;
    float m0 = a0 / cn, m1 = a1 / cn, m2 = a2 / cn, m3 = a3 / cn;
    float ss = m0 * m0 + m1 * m1 + m2 * m2 + m3 * m3;
    #pragma unroll
    for (int o = 32; o > 0; o >>= 1) ss += __shfl_xor(ss, o, 64);
    bool z = (ss == 0.f);                      // no-in-edge node: zero_mask -> ones
    float inv = 1.f / fmaxf(z ? 16.f : sqrtf(ss), EPSF);
    float o0 = (z ? 1.f : m0) * inv, o1 = (z ? 1.f : m1) * inv;
    float o2 = (z ? 1.f : m2) * inv, o3 = (z ? 1.f : m3) * inv;

    float4 s4 = reinterpret_cast<const float4*>(selfb + (size_t)wid * 256)[lane];
    float v0 = 0.5f * (s4.x + o0), v1 = 0.5f * (s4.y + o1);   // t==1.0f in fp32
    float v2 = 0.5f * (s4.z + o2), v3 = 0.5f * (s4.w + o3);
    float ss2 = v0 * v0 + v1 * v1 + v2 * v2 + v3 * v3;
    #pragma unroll
    for (int o = 32; o > 0; o >>= 1) ss2 += __shfl_xor(ss2, o, 64);
    bool z2 = (ss2 == 0.f);
    float inv2 = 1.f / fmaxf(z2 ? 16.f : sqrtf(ss2), EPSF);

    float* op = out + (size_t)wid * 257 + lane * 4;
    op[0] = (z2 ? 1.f : v0) * inv2;
    op[1] = (z2 ? 1.f : v1) * inv2;
    op[2] = (z2 ? 1.f : v2) * inv2;
    op[3] = (z2 ? 1.f : v3) * inv2;
    if (lane == 0) out[(size_t)wid * 257 + 256] = 0.5f * (xh[wid] + 1.f + ah);
}

extern "C" void kernel_launch(void* const* d_in, const int* in_sizes, int n_in,
                              void* d_out, int out_size, void* d_ws, size_t ws_size,
                              hipStream_t stream) {
    const float* x  = (const float*)d_in[0];
    const float* Ws = (const float*)d_in[1];
    const float* Wn = (const float*)d_in[2];
    const int*   ei = (const int*)d_in[3];
    int N = in_sizes[0] / 257;
    int E = in_sizes[3] / 2;
    float* out = (float*)d_out;

    char* ws = (char*)d_ws;
    size_t off = 0;
    auto alloc = [&](size_t bytes) {
        void* p = ws + off;
        off = (off + bytes + 255) & ~(size_t)255;
        return p;
    };
    unsigned short* xnb = (unsigned short*)alloc((size_t)N * 256 * 2);
    unsigned short* Wsb = (unsigned short*)alloc(256 * 256 * 2);
    unsigned short* Wnb = (unsigned short*)alloc(256 * 256 * 2);
    float* xh    = (float*)alloc((size_t)N * 4);
    unsigned char* yb8 = (unsigned char*)alloc((size_t)N * 256);
    float* selfb = (float*)alloc((size_t)N * 256 * 4);
    int* hist   = (int*)alloc((size_t)N * 4);
    int* offs   = (int*)alloc((size_t)N * 4);
    int* cursor = (int*)alloc((size_t)N * 4);
    int* scol   = (int*)alloc((size_t)E * 4);

    hipMemsetAsync(hist, 0, (size_t)N * 4, stream);

    // fused prep + W-convert + histogram
    hipLaunchKernelGGL(k_front, dim3(N + 256 + 128), dim3(256), 0, stream,
                       x, Ws, Wn, ei, xnb, xh, Wsb, Wnb, hist, N, E);
    // CSR finish
    hipLaunchKernelGGL(k_scan, dim3(1), dim3(1024), 0, stream, hist, offs, cursor, N);
    hipLaunchKernelGGL(k_bucket, dim3((E + 255) / 256), dim3(256), 0, stream, ei, cursor, scol, E);
    // fused double GEMM + row-normalize
    hipLaunchKernelGGL(k_gemm2, dim3((N + 31) / 32), dim3(512), 0, stream,
                       xnb, Wsb, Wnb, selfb, yb8, N);
    // wave-per-node gather-aggregate + combine
    hipLaunchKernelGGL(k_agg_combine, dim3((N + 3) / 4), dim3(256), 0, stream,
                       offs, hist, scol, yb8, xh, selfb, out, N);
}

// Round 7
// 190.543 us; speedup vs baseline: 1.3253x; 1.0772x over previous
//
#include <hip/hip_runtime.h>
#include <hip/hip_bf16.h>

#define EPSF 1e-8f

typedef __attribute__((ext_vector_type(4))) float floatx4;
typedef __attribute__((ext_vector_type(2))) float floatx2;

__device__ inline unsigned short f2bf(float v) {
    union { float f; unsigned int u; } un; un.f = v;
    unsigned int r = (un.u + 0x7fffu + ((un.u >> 16) & 1u)) >> 16;
    return (unsigned short)r;
}
__device__ inline float bf2f(unsigned short u) {
    union { unsigned int i; float f; } un; un.i = ((unsigned int)u) << 16;
    return un.f;
}

// ---- fp8 e4m3 (OCP) helpers: HW cvt on gfx950, SW fallback otherwise ----
__device__ inline unsigned char f2fp8(float v) {
#if __has_builtin(__builtin_amdgcn_cvt_pk_fp8_f32)
    return (unsigned char)(__builtin_amdgcn_cvt_pk_fp8_f32(v, 0.f, 0u, false) & 0xff);
#else
    union { float f; unsigned u; } x; x.f = v;
    unsigned s = x.u >> 31; x.u &= 0x7fffffffu;
    if (x.f != x.f || x.f == 0.f) return (unsigned char)(s << 7);
    int e = (int)((x.u >> 23) & 0xff) - 127 + 7;
    unsigned m = x.u & 0x7fffffu;
    unsigned char r;
    if (e >= 1) {
        unsigned keep = m >> 20, rest = m & 0xfffffu;
        keep += (rest > 0x80000u) || (rest == 0x80000u && (keep & 1));
        if (keep == 8) { keep = 0; e += 1; }
        if (e > 15) { e = 15; keep = 6; }
        r = (unsigned char)((e << 3) | keep);
    } else {
        int q = (int)(x.f * 512.f + 0.5f);
        if (q > 7) r = 0x08; else r = (unsigned char)q;
    }
    return (unsigned char)(r | (s << 7));
#endif
}
__device__ inline unsigned pk_fp8x4(float v0, float v1, float v2, float v3) {
#if __has_builtin(__builtin_amdgcn_cvt_pk_fp8_f32)
    unsigned u = __builtin_amdgcn_cvt_pk_fp8_f32(v0, v1, 0u, false);
    u = __builtin_amdgcn_cvt_pk_fp8_f32(v2, v3, u, true);
    return u;
#else
    return (unsigned)f2fp8(v0) | ((unsigned)f2fp8(v1) << 8)
         | ((unsigned)f2fp8(v2) << 16) | ((unsigned)f2fp8(v3) << 24);
#endif
}
__device__ inline floatx2 fp8x2_to_f32(unsigned int u, bool word) {
#if __has_builtin(__builtin_amdgcn_cvt_pk_f32_fp8)
    return word ? __builtin_amdgcn_cvt_pk_f32_fp8(u, true)
                : __builtin_amdgcn_cvt_pk_f32_fp8(u, false);
#else
    floatx2 out;
    #pragma unroll
    for (int i = 0; i < 2; ++i) {
        unsigned char b = (u >> ((word ? 16 : 0) + 8 * i)) & 0xff;
        unsigned s = (b >> 7) & 1, e = (b >> 3) & 15, m = b & 7;
        float v;
        if (e) { union { unsigned u2; float f; } x; x.u2 = (s << 31) | ((e + 120u) << 23) | (m << 20); v = x.f; }
        else   { v = (s ? -1.f : 1.f) * (float)m * 0.001953125f; }
        out[i] = v;
    }
    return out;
#endif
}

// --- K_FRONT: W->fp8 (blocks [0,128)) + xh=|h| (blocks [128,168))
//              + row histogram (blocks [168,296)). 512 threads. ---
__global__ __launch_bounds__(512) void k_front(
        const float* __restrict__ x, const float* __restrict__ Ws,
        const float* __restrict__ Wn, const int* __restrict__ ei,
        unsigned char* __restrict__ Wsf8, unsigned char* __restrict__ Wnf8,
        float* __restrict__ xh, int* __restrict__ hist, int N, int E) {
    int b = blockIdx.x, t = threadIdx.x;
    if (b < 128) {
        int idx = b * 512 + t;                 // 65536 elements per matrix
        Wsf8[idx] = f2fp8(Ws[idx]);
        Wnf8[idx] = f2fp8(Wn[idx]);
    } else if (b < 168) {
        int i = (b - 128) * 512 + t;
        if (i < N) xh[i] = fabsf(x[(size_t)i * 257 + 256]);
    } else {
        for (int e = (b - 168) * 512 + t; e < E; e += 128 * 512)
            atomicAdd(&hist[ei[e]], 1);
    }
}

// --- S2: exclusive prefix sum (single block, wave-shfl scan, 1 barrier) ---
__global__ __launch_bounds__(1024) void k_scan(const int* __restrict__ hist,
        int* __restrict__ offs, int* __restrict__ cursor, int N) {
    __shared__ int wtot[16];
    int t = threadIdx.x, lane = t & 63, wv = t >> 6;
    int C = (N + 1023) >> 10;
    int base = t * C;
    int vals[32];
    int s = 0;
    #pragma unroll
    for (int i = 0; i < 32; ++i) {
        if (i < C) {
            int idx = base + i;
            vals[i] = (idx < N) ? hist[idx] : 0;
            s += vals[i];
        }
    }
    int incl = s;
    #pragma unroll
    for (int o = 1; o < 64; o <<= 1) {
        int v = __shfl_up(incl, o, 64);
        if (lane >= o) incl += v;
    }
    if (lane == 63) wtot[wv] = incl;
    __syncthreads();
    int wbase = 0;
    for (int w = 0; w < wv; ++w) wbase += wtot[w];
    int run = wbase + incl - s;
    #pragma unroll
    for (int i = 0; i < 32; ++i) {
        if (i < C) {
            int idx = base + i;
            if (idx < N) { offs[idx] = run; cursor[idx] = run; run += vals[i]; }
        }
    }
}

// --- K_MID: blocks [0,GB): fp8 double-GEMM + row-normalize (32 rows/block);
//            blocks [GB,GB+EB): CSR bucket + aggh atomics. 512 threads. ---
// GEMM: waves 0-3 -> W_self -> selfb (bf16), 4-7 -> W_neigh -> yb8 (fp8).
// A staged fp32->fp8 in LDS (stride 272: staging stores AND frag reads 2-way).
__global__ __launch_bounds__(512) void k_mid(
        const float* __restrict__ x,
        const unsigned char* __restrict__ Wsf8,
        const unsigned char* __restrict__ Wnf8,
        const int* __restrict__ ei, const float* __restrict__ xh,
        int* __restrict__ cursor, int* __restrict__ scol,
        float* __restrict__ aggh,
        unsigned short* __restrict__ selfb, unsigned char* __restrict__ yb8,
        int N, int E, int GB) {
    __shared__ unsigned char As[32][272];
    __shared__ float pss[8][32];
    __shared__ float sgnS[32];
    int b = blockIdx.x, tid = threadIdx.x;

    if (b >= GB) {                             // ---- bucket part ----
        int e = (b - GB) * 512 + tid;
        if (e < E) {
            int r = ei[e], c = ei[E + e];
            int pos = atomicAdd(&cursor[r], 1);
            scol[pos] = c;
            atomicAdd(&aggh[r], xh[c]);
        }
        return;
    }

    // ---- GEMM part ----
    int wave = tid >> 6, lane = tid & 63;
    int quad = lane >> 4, l16 = lane & 15;
    int mat = wave >> 2, wq = wave & 3;
    int row0 = b * 32;

    if (tid < 32) {
        int gr = row0 + tid; if (gr >= N) gr = N - 1;
        float h = x[(size_t)gr * 257 + 256];
        sgnS[tid] = (h < 0.f) ? -1.f : 1.f;    // sign(0) -> 1 per reference
    }
    __syncthreads();

    // stage A: 32 rows x 256 fp8; 4 passes x 512 threads x (float4 -> 4 fp8)
    #pragma unroll
    for (int p = 0; p < 4; ++p) {
        int c = p * 512 + tid;
        int row = c >> 6, f4 = (c & 63) * 4;
        int gr = row0 + row; if (gr >= N) gr = N - 1;
        float4 v = *reinterpret_cast<const float4*>(x + (size_t)gr * 257 + f4);
        float sg = sgnS[row];
        *reinterpret_cast<unsigned*>(&As[row][f4]) =
            pk_fp8x4(v.x * sg, v.y * sg, v.z * sg, v.w * sg);
    }
    __syncthreads();

    const unsigned char* W  = mat ? Wnf8 : Wsf8;
    const unsigned char* Wp = W + (size_t)(wq * 64 + l16) * 256 + quad * 8;

    floatx4 acc[2][4];                         // [row-tile][col-group]
    #pragma unroll
    for (int rt = 0; rt < 2; ++rt)
        #pragma unroll
        for (int g = 0; g < 4; ++g) acc[rt][g] = floatx4{0.f, 0.f, 0.f, 0.f};

    #pragma unroll
    for (int ks = 0; ks < 256; ks += 32) {
        long a0 = *reinterpret_cast<const long*>(&As[l16][quad * 8 + ks]);
        long a1 = *reinterpret_cast<const long*>(&As[16 + l16][quad * 8 + ks]);
        long w0 = *reinterpret_cast<const long*>(Wp + (size_t)0 * 4096 + ks);
        long w1 = *reinterpret_cast<const long*>(Wp + (size_t)1 * 4096 + ks);
        long w2 = *reinterpret_cast<const long*>(Wp + (size_t)2 * 4096 + ks);
        long w3 = *reinterpret_cast<const long*>(Wp + (size_t)3 * 4096 + ks);
        acc[0][0] = __builtin_amdgcn_mfma_f32_16x16x32_fp8_fp8(a0, w0, acc[0][0], 0, 0, 0);
        acc[1][0] = __builtin_amdgcn_mfma_f32_16x16x32_fp8_fp8(a1, w0, acc[1][0], 0, 0, 0);
        acc[0][1] = __builtin_amdgcn_mfma_f32_16x16x32_fp8_fp8(a0, w1, acc[0][1], 0, 0, 0);
        acc[1][1] = __builtin_amdgcn_mfma_f32_16x16x32_fp8_fp8(a1, w1, acc[1][1], 0, 0, 0);
        acc[0][2] = __builtin_amdgcn_mfma_f32_16x16x32_fp8_fp8(a0, w2, acc[0][2], 0, 0, 0);
        acc[1][2] = __builtin_amdgcn_mfma_f32_16x16x32_fp8_fp8(a1, w2, acc[1][2], 0, 0, 0);
        acc[0][3] = __builtin_amdgcn_mfma_f32_16x16x32_fp8_fp8(a0, w3, acc[0][3], 0, 0, 0);
        acc[1][3] = __builtin_amdgcn_mfma_f32_16x16x32_fp8_fp8(a1, w3, acc[1][3], 0, 0, 0);
    }

    // per-wave row ss partials (C/D: col=16g+l16 (+64wq), row=quad*4+reg)
    #pragma unroll
    for (int rt = 0; rt < 2; ++rt) {
        float s[4];
        #pragma unroll
        for (int reg = 0; reg < 4; ++reg) {
            float v = 0.f;
            #pragma unroll
            for (int g = 0; g < 4; ++g) v += acc[rt][g][reg] * acc[rt][g][reg];
            #pragma unroll
            for (int o = 8; o > 0; o >>= 1) v += __shfl_down(v, o, 64);
            s[reg] = v;
        }
        if (l16 == 0) {
            #pragma unroll
            for (int reg = 0; reg < 4; ++reg)
                pss[wave][rt * 16 + quad * 4 + reg] = s[reg];
        }
    }
    __syncthreads();

    int wb = mat * 4;
    #pragma unroll
    for (int rt = 0; rt < 2; ++rt)
        #pragma unroll
        for (int reg = 0; reg < 4; ++reg) {
            int r32 = rt * 16 + quad * 4 + reg;
            int gr = row0 + r32;
            if (gr >= N) continue;
            float ss = pss[wb][r32] + pss[wb + 1][r32]
                     + pss[wb + 2][r32] + pss[wb + 3][r32];
            bool zero = (ss == 0.f);
            float scale = zero ? 0.f : (1.f / fmaxf(sqrtf(ss), EPSF));
            #pragma unroll
            for (int g = 0; g < 4; ++g) {
                int col = wq * 64 + 16 * g + l16;
                float val = zero ? 0.0625f : acc[rt][g][reg] * scale;
                if (mat == 0) selfb[(size_t)gr * 256 + col] = f2bf(val);
                else          yb8[(size_t)gr * 256 + col] = f2fp8(val);
            }
        }
}

// --- S4: ONE WAVE PER NODE, fp8 gather unrolled x4; wave-local epilogue. ---
__global__ __launch_bounds__(256) void k_agg_combine(
        const int* __restrict__ offs, const int* __restrict__ hist,
        const int* __restrict__ scol, const unsigned char* __restrict__ yb8,
        const float* __restrict__ xh, const float* __restrict__ aggh,
        const unsigned short* __restrict__ selfb,
        float* __restrict__ out, int N) {
    int wid = (blockIdx.x * 256 + threadIdx.x) >> 6;   // global wave = node id
    if (wid >= N) return;
    int lane = threadIdx.x & 63;
    int beg = offs[wid], deg = hist[wid];
    float a0 = 0.f, a1 = 0.f, a2 = 0.f, a3 = 0.f;
    float b0 = 0.f, b1 = 0.f, b2 = 0.f, b3 = 0.f;
    int e = beg, end = beg + deg;
    for (; e + 3 < end; e += 4) {
        int c0 = scol[e], c1 = scol[e + 1], c2 = scol[e + 2], c3 = scol[e + 3];
        unsigned u0 = *reinterpret_cast<const unsigned*>(yb8 + (size_t)c0 * 256 + lane * 4);
        unsigned u1 = *reinterpret_cast<const unsigned*>(yb8 + (size_t)c1 * 256 + lane * 4);
        unsigned u2 = *reinterpret_cast<const unsigned*>(yb8 + (size_t)c2 * 256 + lane * 4);
        unsigned u3 = *reinterpret_cast<const unsigned*>(yb8 + (size_t)c3 * 256 + lane * 4);
        floatx2 p;
        p = fp8x2_to_f32(u0, false); a0 += p[0]; a1 += p[1];
        p = fp8x2_to_f32(u0, true);  a2 += p[0]; a3 += p[1];
        p = fp8x2_to_f32(u1, false); b0 += p[0]; b1 += p[1];
        p = fp8x2_to_f32(u1, true);  b2 += p[0]; b3 += p[1];
        p = fp8x2_to_f32(u2, false); a0 += p[0]; a1 += p[1];
        p = fp8x2_to_f32(u2, true);  a2 += p[0]; a3 += p[1];
        p = fp8x2_to_f32(u3, false); b0 += p[0]; b1 += p[1];
        p = fp8x2_to_f32(u3, true);  b2 += p[0]; b3 += p[1];
    }
    for (; e < end; ++e) {
        int c0 = scol[e];
        unsigned u0 = *reinterpret_cast<const unsigned*>(yb8 + (size_t)c0 * 256 + lane * 4);
        floatx2 p;
        p = fp8x2_to_f32(u0, false); a0 += p[0]; a1 += p[1];
        p = fp8x2_to_f32(u0, true);  a2 += p[0]; a3 += p[1];
    }
    a0 += b0; a1 += b1; a2 += b2; a3 += b3;

    float cn = (deg > 0) ? (float)deg : 1.f;
    float m0 = a0 / cn, m1 = a1 / cn, m2 = a2 / cn, m3 = a3 / cn;
    float ss = m0 * m0 + m1 * m1 + m2 * m2 + m3 * m3;
    #pragma unroll
    for (int o = 32; o > 0; o >>= 1) ss += __shfl_xor(ss, o, 64);
    bool z = (ss == 0.f);                      // no-in-edge node: zero_mask -> ones
    float inv = 1.f / fmaxf(z ? 16.f : sqrtf(ss), EPSF);
    float o0 = (z ? 1.f : m0) * inv, o1 = (z ? 1.f : m1) * inv;
    float o2 = (z ? 1.f : m2) * inv, o3 = (z ? 1.f : m3) * inv;

    ushort4 s4 = *reinterpret_cast<const ushort4*>(selfb + (size_t)wid * 256 + lane * 4);
    float v0 = 0.5f * (bf2f(s4.x) + o0), v1 = 0.5f * (bf2f(s4.y) + o1);  // t==1.0f
    float v2 = 0.5f * (bf2f(s4.z) + o2), v3 = 0.5f * (bf2f(s4.w) + o3);
    float ss2 = v0 * v0 + v1 * v1 + v2 * v2 + v3 * v3;
    #pragma unroll
    for (int o = 32; o > 0; o >>= 1) ss2 += __shfl_xor(ss2, o, 64);
    bool z2 = (ss2 == 0.f);
    float inv2 = 1.f / fmaxf(z2 ? 16.f : sqrtf(ss2), EPSF);

    float* op = out + (size_t)wid * 257 + lane * 4;
    op[0] = (z2 ? 1.f : v0) * inv2;
    op[1] = (z2 ? 1.f : v1) * inv2;
    op[2] = (z2 ? 1.f : v2) * inv2;
    op[3] = (z2 ? 1.f : v3) * inv2;
    if (lane == 0) out[(size_t)wid * 257 + 256] = 0.5f * (xh[wid] + 1.f + aggh[wid]);
}

extern "C" void kernel_launch(void* const* d_in, const int* in_sizes, int n_in,
                              void* d_out, int out_size, void* d_ws, size_t ws_size,
                              hipStream_t stream) {
    const float* x  = (const float*)d_in[0];
    const float* Ws = (const float*)d_in[1];
    const float* Wn = (const float*)d_in[2];
    const int*   ei = (const int*)d_in[3];
    int N = in_sizes[0] / 257;
    int E = in_sizes[3] / 2;
    float* out = (float*)d_out;

    char* ws = (char*)d_ws;
    size_t off = 0;
    auto alloc = [&](size_t bytes) {
        void* p = ws + off;
        off = (off + bytes + 255) & ~(size_t)255;
        return p;
    };
    unsigned char* Wsf8 = (unsigned char*)alloc(256 * 256);
    unsigned char* Wnf8 = (unsigned char*)alloc(256 * 256);
    float* xh    = (float*)alloc((size_t)N * 4);
    unsigned char* yb8 = (unsigned char*)alloc((size_t)N * 256);
    unsigned short* selfb = (unsigned short*)alloc((size_t)N * 256 * 2);
    int* hist   = (int*)alloc((size_t)N * 4);
    float* aggh = (float*)alloc((size_t)N * 4);
    int* offs   = (int*)alloc((size_t)N * 4);
    int* cursor = (int*)alloc((size_t)N * 4);
    int* scol   = (int*)alloc((size_t)E * 4);

    // zero hist..aggh (contiguous region)
    size_t zbytes = (size_t)((char*)aggh + (size_t)N * 4 - (char*)hist);
    hipMemsetAsync(hist, 0, zbytes, stream);

    // W->fp8 + xh + histogram
    hipLaunchKernelGGL(k_front, dim3(296), dim3(512), 0, stream,
                       x, Ws, Wn, ei, Wsf8, Wnf8, xh, hist, N, E);
    // prefix sum
    hipLaunchKernelGGL(k_scan, dim3(1), dim3(1024), 0, stream, hist, offs, cursor, N);
    // fused: fp8 double-GEMM (+row-normalize) || CSR bucket (+aggh)
    int GB = (N + 31) / 32, EB = (E + 511) / 512;
    hipLaunchKernelGGL(k_mid, dim3(GB + EB), dim3(512), 0, stream,
                       x, Wsf8, Wnf8, ei, xh, cursor, scol, aggh, selfb, yb8, N, E, GB);
    // wave-per-node gather-aggregate + combine
    hipLaunchKernelGGL(k_agg_combine, dim3((N + 3) / 4), dim3(256), 0, stream,
                       offs, hist, scol, yb8, xh, aggh, selfb, out, N);
}

// Round 9
// 180.358 us; speedup vs baseline: 1.4001x; 1.0565x over previous
//
#include <hip/hip_runtime.h>
#include <hip/hip_bf16.h>

#define EPSF 1e-8f

typedef __attribute__((ext_vector_type(4))) float floatx4;
typedef __attribute__((ext_vector_type(2))) float floatx2;
typedef __attribute__((ext_vector_type(2))) long longx2;

__device__ inline unsigned short f2bf(float v) {
    union { float f; unsigned int u; } un; un.f = v;
    unsigned int r = (un.u + 0x7fffu + ((un.u >> 16) & 1u)) >> 16;
    return (unsigned short)r;
}
__device__ inline float bf2f(unsigned short u) {
    union { unsigned int i; float f; } un; un.i = ((unsigned int)u) << 16;
    return un.f;
}

// ---- fp8 e4m3 (OCP) helpers: HW cvt on gfx950, SW fallback otherwise ----
__device__ inline unsigned char f2fp8(float v) {
#if __has_builtin(__builtin_amdgcn_cvt_pk_fp8_f32)
    return (unsigned char)(__builtin_amdgcn_cvt_pk_fp8_f32(v, 0.f, 0u, false) & 0xff);
#else
    union { float f; unsigned u; } x; x.f = v;
    unsigned s = x.u >> 31; x.u &= 0x7fffffffu;
    if (x.f != x.f || x.f == 0.f) return (unsigned char)(s << 7);
    int e = (int)((x.u >> 23) & 0xff) - 127 + 7;
    unsigned m = x.u & 0x7fffffu;
    unsigned char r;
    if (e >= 1) {
        unsigned keep = m >> 20, rest = m & 0xfffffu;
        keep += (rest > 0x80000u) || (rest == 0x80000u && (keep & 1));
        if (keep == 8) { keep = 0; e += 1; }
        if (e > 15) { e = 15; keep = 6; }
        r = (unsigned char)((e << 3) | keep);
    } else {
        int q = (int)(x.f * 512.f + 0.5f);
        if (q > 7) r = 0x08; else r = (unsigned char)q;
    }
    return (unsigned char)(r | (s << 7));
#endif
}
__device__ inline unsigned pk_fp8x4(float v0, float v1, float v2, float v3) {
#if __has_builtin(__builtin_amdgcn_cvt_pk_fp8_f32)
    unsigned u = __builtin_amdgcn_cvt_pk_fp8_f32(v0, v1, 0u, false);
    u = __builtin_amdgcn_cvt_pk_fp8_f32(v2, v3, u, true);
    return u;
#else
    return (unsigned)f2fp8(v0) | ((unsigned)f2fp8(v1) << 8)
         | ((unsigned)f2fp8(v2) << 16) | ((unsigned)f2fp8(v3) << 24);
#endif
}
__device__ inline floatx2 fp8x2_to_f32(unsigned int u, bool word) {
#if __has_builtin(__builtin_amdgcn_cvt_pk_f32_fp8)
    return word ? __builtin_amdgcn_cvt_pk_f32_fp8(u, true)
                : __builtin_amdgcn_cvt_pk_f32_fp8(u, false);
#else
    floatx2 out;
    #pragma unroll
    for (int i = 0; i < 2; ++i) {
        unsigned char b = (u >> ((word ? 16 : 0) + 8 * i)) & 0xff;
        unsigned s = (b >> 7) & 1, e = (b >> 3) & 15, m = b & 7;
        float v;
        if (e) { union { unsigned u2; float f; } x; x.u2 = (s << 31) | ((e + 120u) << 23) | (m << 20); v = x.f; }
        else   { v = (s ? -1.f : 1.f) * (float)m * 0.001953125f; }
        out[i] = v;
    }
    return out;
#endif
}

// --- K_FRONT: W->fp8 frag-swizzled (blocks [0,32), 16384 u32 PER MATRIX)
//              + xh=|h| (XB blocks) + row histogram (128 blocks). ---
// W swizzle: u32 index idx = wq<<12 | g<<10 | p<<8 | lane<<2 | t4 (14 bits),
// holding fp8 of W[row=wq*64+g*16+(lane&15)][k0..k0+4), k0 = 32*(2p+(t0>>3))
// + 8*(lane>>4) + (t0&7), t0=4*t4. K-loop loads 16B/lane, 64-lane contiguous.
__global__ __launch_bounds__(512) void k_front(
        const float* __restrict__ x, const float* __restrict__ Ws,
        const float* __restrict__ Wn, const int* __restrict__ ei,
        unsigned char* __restrict__ Wswz,
        float* __restrict__ xh, int* __restrict__ hist, int N, int E, int XB) {
    int b = blockIdx.x, t = threadIdx.x;
    if (b < 32) {
        int idx = b * 512 + t;                 // [0, 16384) per-mat u32 index
        int t0 = (idx & 3) * 4;                // byte offset in 16B unit
        int lane = (idx >> 2) & 63;
        int p = (idx >> 8) & 3;
        int g = (idx >> 10) & 3;
        int wq = (idx >> 12) & 3;
        int q = lane >> 4, l16 = lane & 15;
        int row = wq * 64 + g * 16 + l16;
        int s = 2 * p + (t0 >> 3);
        int k0 = 32 * s + 8 * q + (t0 & 7);
        float4 vs = *reinterpret_cast<const float4*>(Ws + row * 256 + k0);
        float4 vn = *reinterpret_cast<const float4*>(Wn + row * 256 + k0);
        reinterpret_cast<unsigned*>(Wswz)[idx] = pk_fp8x4(vs.x, vs.y, vs.z, vs.w);
        reinterpret_cast<unsigned*>(Wswz)[16384 + idx] = pk_fp8x4(vn.x, vn.y, vn.z, vn.w);
    } else if (b < 32 + XB) {
        int i = (b - 32) * 512 + t;
        if (i < N) xh[i] = fabsf(x[(size_t)i * 257 + 256]);
    } else {
        for (int e = (b - 32 - XB) * 512 + t; e < E; e += 128 * 512)
            atomicAdd(&hist[ei[e]], 1);
    }
}

// --- S2: exclusive prefix sum (single block, wave-shfl scan, 1 barrier) ---
__global__ __launch_bounds__(1024) void k_scan(const int* __restrict__ hist,
        int* __restrict__ offs, int* __restrict__ cursor, int N) {
    __shared__ int wtot[16];
    int t = threadIdx.x, lane = t & 63, wv = t >> 6;
    int C = (N + 1023) >> 10;
    int base = t * C;
    int vals[32];
    int s = 0;
    #pragma unroll
    for (int i = 0; i < 32; ++i) {
        if (i < C) {
            int idx = base + i;
            vals[i] = (idx < N) ? hist[idx] : 0;
            s += vals[i];
        }
    }
    int incl = s;
    #pragma unroll
    for (int o = 1; o < 64; o <<= 1) {
        int v = __shfl_up(incl, o, 64);
        if (lane >= o) incl += v;
    }
    if (lane == 63) wtot[wv] = incl;
    __syncthreads();
    int wbase = 0;
    for (int w = 0; w < wv; ++w) wbase += wtot[w];
    int run = wbase + incl - s;
    #pragma unroll
    for (int i = 0; i < 32; ++i) {
        if (i < C) {
            int idx = base + i;
            if (idx < N) { offs[idx] = run; cursor[idx] = run; run += vals[i]; }
        }
    }
}

// --- K_MID: blocks [0,GB): fp8 double-GEMM + row-normalize (32 rows/block);
//            blocks [GB,GB+EB): CSR bucket + aggh atomics. 512 threads. ---
// GEMM: waves 0-3 -> W_self -> selfb (bf16), 4-7 -> W_neigh -> yb8 (fp8).
// W in frag-swizzled layout (16B/lane dwordx4, coalesced). A staged fp32->fp8
// in LDS, k-pair layout + per-row 16B rotation (bank-spread), ds_read_b128.
__global__ __launch_bounds__(512, 4) void k_mid(
        const float* __restrict__ x,
        const unsigned char* __restrict__ Wswz,
        const int* __restrict__ ei, const float* __restrict__ xh,
        int* __restrict__ cursor, int* __restrict__ scol,
        float* __restrict__ aggh,
        unsigned short* __restrict__ selfb, unsigned char* __restrict__ yb8,
        int N, int E, int GB) {
    __shared__ __align__(16) unsigned char As[32][256];
    __shared__ float pss[8][32];
    __shared__ float sgnS[32];
    int b = blockIdx.x, tid = threadIdx.x;

    if (b >= GB) {                             // ---- bucket part ----
        int e = (b - GB) * 512 + tid;
        if (e < E) {
            int r = ei[e], c = ei[E + e];
            int pos = atomicAdd(&cursor[r], 1);
            scol[pos] = c;
            atomicAdd(&aggh[r], xh[c]);
        }
        return;
    }

    // ---- GEMM part ----
    int wave = tid >> 6, lane = tid & 63;
    int quad = lane >> 4, l16 = lane & 15;
    int mat = wave >> 2, wq = wave & 3;
    int row0 = b * 32;

    if (tid < 32) {
        int gr = row0 + tid; if (gr >= N) gr = N - 1;
        float h = x[(size_t)gr * 257 + 256];
        sgnS[tid] = (h < 0.f) ? -1.f : 1.f;    // sign(0) -> 1 per reference
    }
    __syncthreads();

    // stage A: 32 rows x 256 fp8, k-pair layout + row rotation
    #pragma unroll
    for (int ps = 0; ps < 4; ++ps) {
        int c = ps * 512 + tid;
        int row = c >> 6, k0 = (c & 63) * 4;
        int gr = row0 + row; if (gr >= N) gr = N - 1;
        float4 v = *reinterpret_cast<const float4*>(x + (size_t)gr * 257 + k0);
        float sg = sgnS[row];
        int s = k0 >> 5, q = (k0 >> 3) & 3, j0 = k0 & 7;
        int dst = (q * 64 + (s >> 1) * 16 + (s & 1) * 8 + j0 + row * 16) & 255;
        *reinterpret_cast<unsigned*>(&As[row][dst]) =
            pk_fp8x4(v.x * sg, v.y * sg, v.z * sg, v.w * sg);
    }
    __syncthreads();

    const unsigned char* Wb = Wswz + ((size_t)mat << 16) + ((size_t)wq << 14);
    int rowA = l16, rowB = 16 + l16;

    floatx4 acc[2][4];                         // [row-tile][col-group]
    #pragma unroll
    for (int rt = 0; rt < 2; ++rt)
        #pragma unroll
        for (int g = 0; g < 4; ++g) acc[rt][g] = floatx4{0.f, 0.f, 0.f, 0.f};

    #pragma unroll
    for (int p = 0; p < 4; ++p) {              // k-pair: k-steps 2p, 2p+1
        longx2 a0 = *reinterpret_cast<const longx2*>(
            &As[rowA][(quad * 64 + p * 16 + rowA * 16) & 255]);
        longx2 a1 = *reinterpret_cast<const longx2*>(
            &As[rowB][(quad * 64 + p * 16 + rowB * 16) & 255]);
        #pragma unroll
        for (int g = 0; g < 4; ++g) {
            longx2 w = *reinterpret_cast<const longx2*>(
                Wb + (((g * 4 + p) * 64 + lane) << 4));
            acc[0][g] = __builtin_amdgcn_mfma_f32_16x16x32_fp8_fp8(a0[0], w[0], acc[0][g], 0, 0, 0);
            acc[1][g] = __builtin_amdgcn_mfma_f32_16x16x32_fp8_fp8(a1[0], w[0], acc[1][g], 0, 0, 0);
            acc[0][g] = __builtin_amdgcn_mfma_f32_16x16x32_fp8_fp8(a0[1], w[1], acc[0][g], 0, 0, 0);
            acc[1][g] = __builtin_amdgcn_mfma_f32_16x16x32_fp8_fp8(a1[1], w[1], acc[1][g], 0, 0, 0);
        }
    }

    // per-wave row ss partials (C/D: col=16g+l16 (+64wq), row=quad*4+reg)
    #pragma unroll
    for (int rt = 0; rt < 2; ++rt) {
        float s[4];
        #pragma unroll
        for (int reg = 0; reg < 4; ++reg) {
            float v = 0.f;
            #pragma unroll
            for (int g = 0; g < 4; ++g) v += acc[rt][g][reg] * acc[rt][g][reg];
            #pragma unroll
            for (int o = 8; o > 0; o >>= 1) v += __shfl_down(v, o, 64);
            s[reg] = v;
        }
        if (l16 == 0) {
            #pragma unroll
            for (int reg = 0; reg < 4; ++reg)
                pss[wave][rt * 16 + quad * 4 + reg] = s[reg];
        }
    }
    __syncthreads();

    int wb = mat * 4;
    #pragma unroll
    for (int rt = 0; rt < 2; ++rt)
        #pragma unroll
        for (int reg = 0; reg < 4; ++reg) {
            int r32 = rt * 16 + quad * 4 + reg;
            int gr = row0 + r32;
            if (gr >= N) continue;
            float ss = pss[wb][r32] + pss[wb + 1][r32]
                     + pss[wb + 2][r32] + pss[wb + 3][r32];
            bool zero = (ss == 0.f);
            float scale = zero ? 0.f : (1.f / fmaxf(sqrtf(ss), EPSF));
            #pragma unroll
            for (int g = 0; g < 4; ++g) {
                int col = wq * 64 + 16 * g + l16;
                float val = zero ? 0.0625f : acc[rt][g][reg] * scale;
                if (mat == 0) selfb[(size_t)gr * 256 + col] = f2bf(val);
                else          yb8[(size_t)gr * 256 + col] = f2fp8(val);
            }
        }
}

// --- S4: ONE WAVE PER NODE, fp8 gather unrolled x4; wave-local epilogue. ---
__global__ __launch_bounds__(256) void k_agg_combine(
        const int* __restrict__ offs, const int* __restrict__ hist,
        const int* __restrict__ scol, const unsigned char* __restrict__ yb8,
        const float* __restrict__ xh, const float* __restrict__ aggh,
        const unsigned short* __restrict__ selfb,
        float* __restrict__ out, int N) {
    int wid = (blockIdx.x * 256 + threadIdx.x) >> 6;   // global wave = node id
    if (wid >= N) return;
    int lane = threadIdx.x & 63;
    int beg = offs[wid], deg = hist[wid];
    float a0 = 0.f, a1 = 0.f, a2 = 0.f, a3 = 0.f;
    float b0 = 0.f, b1 = 0.f, b2 = 0.f, b3 = 0.f;
    int e = beg, end = beg + deg;
    for (; e + 3 < end; e += 4) {
        int c0 = scol[e], c1 = scol[e + 1], c2 = scol[e + 2], c3 = scol[e + 3];
        unsigned u0 = *reinterpret_cast<const unsigned*>(yb8 + (size_t)c0 * 256 + lane * 4);
        unsigned u1 = *reinterpret_cast<const unsigned*>(yb8 + (size_t)c1 * 256 + lane * 4);
        unsigned u2 = *reinterpret_cast<const unsigned*>(yb8 + (size_t)c2 * 256 + lane * 4);
        unsigned u3 = *reinterpret_cast<const unsigned*>(yb8 + (size_t)c3 * 256 + lane * 4);
        floatx2 p;
        p = fp8x2_to_f32(u0, false); a0 += p[0]; a1 += p[1];
        p = fp8x2_to_f32(u0, true);  a2 += p[0]; a3 += p[1];
        p = fp8x2_to_f32(u1, false); b0 += p[0]; b1 += p[1];
        p = fp8x2_to_f32(u1, true);  b2 += p[0]; b3 += p[1];
        p = fp8x2_to_f32(u2, false); a0 += p[0]; a1 += p[1];
        p = fp8x2_to_f32(u2, true);  a2 += p[0]; a3 += p[1];
        p = fp8x2_to_f32(u3, false); b0 += p[0]; b1 += p[1];
        p = fp8x2_to_f32(u3, true);  b2 += p[0]; b3 += p[1];
    }
    for (; e < end; ++e) {
        int c0 = scol[e];
        unsigned u0 = *reinterpret_cast<const unsigned*>(yb8 + (size_t)c0 * 256 + lane * 4);
        floatx2 p;
        p = fp8x2_to_f32(u0, false); a0 += p[0]; a1 += p[1];
        p = fp8x2_to_f32(u0, true);  a2 += p[0]; a3 += p[1];
    }
    a0 += b0; a1 += b1; a2 += b2; a3 += b3;

    float cn = (deg > 0) ? (float)deg : 1.f;
    float m0 = a0 / cn, m1 = a1 / cn, m2 = a2 / cn, m3 = a3 / cn;
    float ss = m0 * m0 + m1 * m1 + m2 * m2 + m3 * m3;
    #pragma unroll
    for (int o = 32; o > 0; o >>= 1) ss += __shfl_xor(ss, o, 64);
    bool z = (ss == 0.f);                      // no-in-edge node: zero_mask -> ones
    float inv = 1.f / fmaxf(z ? 16.f : sqrtf(ss), EPSF);
    float o0 = (z ? 1.f : m0) * inv, o1 = (z ? 1.f : m1) * inv;
    float o2 = (z ? 1.f : m2) * inv, o3 = (z ? 1.f : m3) * inv;

    ushort4 s4 = *reinterpret_cast<const ushort4*>(selfb + (size_t)wid * 256 + lane * 4);
    float v0 = 0.5f * (bf2f(s4.x) + o0), v1 = 0.5f * (bf2f(s4.y) + o1);  // t==1.0f
    float v2 = 0.5f * (bf2f(s4.z) + o2), v3 = 0.5f * (bf2f(s4.w) + o3);
    float ss2 = v0 * v0 + v1 * v1 + v2 * v2 + v3 * v3;
    #pragma unroll
    for (int o = 32; o > 0; o >>= 1) ss2 += __shfl_xor(ss2, o, 64);
    bool z2 = (ss2 == 0.f);
    float inv2 = 1.f / fmaxf(z2 ? 16.f : sqrtf(ss2), EPSF);

    float* op = out + (size_t)wid * 257 + lane * 4;
    op[0] = (z2 ? 1.f : v0) * inv2;
    op[1] = (z2 ? 1.f : v1) * inv2;
    op[2] = (z2 ? 1.f : v2) * inv2;
    op[3] = (z2 ? 1.f : v3) * inv2;
    if (lane == 0) out[(size_t)wid * 257 + 256] = 0.5f * (xh[wid] + 1.f + aggh[wid]);
}

extern "C" void kernel_launch(void* const* d_in, const int* in_sizes, int n_in,
                              void* d_out, int out_size, void* d_ws, size_t ws_size,
                              hipStream_t stream) {
    const float* x  = (const float*)d_in[0];
    const float* Ws = (const float*)d_in[1];
    const float* Wn = (const float*)d_in[2];
    const int*   ei = (const int*)d_in[3];
    int N = in_sizes[0] / 257;
    int E = in_sizes[3] / 2;
    float* out = (float*)d_out;

    char* ws = (char*)d_ws;
    size_t off = 0;
    auto alloc = [&](size_t bytes) {
        void* p = ws + off;
        off = (off + bytes + 255) & ~(size_t)255;
        return p;
    };
    unsigned char* Wswz = (unsigned char*)alloc(131072);   // both mats, frag-swizzled
    float* xh    = (float*)alloc((size_t)N * 4);
    unsigned char* yb8 = (unsigned char*)alloc((size_t)N * 256);
    unsigned short* selfb = (unsigned short*)alloc((size_t)N * 256 * 2);
    int* hist   = (int*)alloc((size_t)N * 4);
    float* aggh = (float*)alloc((size_t)N * 4);
    int* offs   = (int*)alloc((size_t)N * 4);
    int* cursor = (int*)alloc((size_t)N * 4);
    int* scol   = (int*)alloc((size_t)E * 4);

    // zero hist..aggh (contiguous region)
    size_t zbytes = (size_t)((char*)aggh + (size_t)N * 4 - (char*)hist);
    hipMemsetAsync(hist, 0, zbytes, stream);

    // W swizzle + xh + histogram
    int XB = (N + 511) / 512;
    hipLaunchKernelGGL(k_front, dim3(32 + XB + 128), dim3(512), 0, stream,
                       x, Ws, Wn, ei, Wswz, xh, hist, N, E, XB);
    // prefix sum
    hipLaunchKernelGGL(k_scan, dim3(1), dim3(1024), 0, stream, hist, offs, cursor, N);
    // fused: fp8 double-GEMM (+row-normalize) || CSR bucket (+aggh)
    int GB = (N + 31) / 32, EB = (E + 511) / 512;
    hipLaunchKernelGGL(k_mid, dim3(GB + EB), dim3(512), 0, stream,
                       x, Wswz, ei, xh, cursor, scol, aggh, selfb, yb8, N, E, GB);
    // wave-per-node gather-aggregate + combine
    hipLaunchKernelGGL(k_agg_combine, dim3((N + 3) / 4), dim3(256), 0, stream,
                       offs, hist, scol, yb8, xh, aggh, selfb, out, N);
}